// Round 5
// baseline (87.425 us; speedup 1.0000x reference)
//
#include <hip/hip_runtime.h>
#include <hip/hip_bf16.h>

#define BB 2
#define TT 15
#define NN 2048
#define TO 8
#define MM 64
#define KH 32
#define DIMD 512
#define R2 0.49f

// DPP cross-lane helpers (VALU, ~4cy — replaces ds_bpermute ~130cy)
template<int CTRL>
__device__ __forceinline__ float dppf(float x) {
    return __int_as_float(__builtin_amdgcn_update_dpp(
        __float_as_int(x), __float_as_int(x), CTRL, 0xF, 0xF, false));
}
template<int CTRL>
__device__ __forceinline__ unsigned dppu(unsigned x) {
    return (unsigned)__builtin_amdgcn_update_dpp((int)x, (int)x, CTRL, 0xF, 0xF, false);
}

// key = (bits(v) << 32) | (2048 - i): u64 max == (max v, tie -> min index).
// v >= 0 always (squared distances), so float bits are order-isomorphic.
__device__ __forceinline__ bool keyGT(unsigned ahi, unsigned alo, unsigned bhi, unsigned blo) {
    unsigned long long a = (((unsigned long long)ahi) << 32) | alo;
    unsigned long long b = (((unsigned long long)bhi) << 32) | blo;
    return a > b;
}

// ---------------- FPS v4: u64 keys + tree scan + packed LDS combine ----------------
// one block per (b,f) frame; orig frame t = 2f
__global__ __launch_bounds__(256) void fps_kernel(const float* __restrict__ input,
                                                  float* __restrict__ anchor_xyz) {
    __shared__ float4 sA[2][4];   // (keyhi, keylo, x, y) per wave
    __shared__ float  sB[2][4];   // z per wave
    int blk = blockIdx.x;            // 0..15 = b*8+f
    int b = blk >> 3, f = blk & 7;
    const float* src = input + ((size_t)(b * TT + 2 * f)) * NN * 3;
    int tid = threadIdx.x, w = tid >> 6;

    // thread t owns consecutive points [8t, 8t+8) in registers
    float px[8], py[8], pz[8], mind[8];
    unsigned lo_[8];                 // 2048 - global_index, precomputed
    const float4* s4 = (const float4*)(src + tid * 24);
    float4 v0 = s4[0], v1 = s4[1], v2 = s4[2], v3 = s4[3], v4 = s4[4], v5 = s4[5];
    px[0] = v0.x; py[0] = v0.y; pz[0] = v0.z;
    px[1] = v0.w; py[1] = v1.x; pz[1] = v1.y;
    px[2] = v1.z; py[2] = v1.w; pz[2] = v2.x;
    px[3] = v2.y; py[3] = v2.z; pz[3] = v2.w;
    px[4] = v3.x; py[4] = v3.y; pz[4] = v3.z;
    px[5] = v3.w; py[5] = v4.x; pz[5] = v4.y;
    px[6] = v4.z; py[6] = v4.w; pz[6] = v5.x;
    px[7] = v5.y; py[7] = v5.z; pz[7] = v5.w;
#pragma unroll
    for (int j = 0; j < 8; ++j) {
        mind[j] = 1e10f;
        lo_[j] = (unsigned)(NN - (tid * 8 + j));
    }

    // seed: point 0 (uniform scalar loads, broadcast)
    float lx = src[0], ly = src[1], lz = src[2];
    float* out = anchor_xyz + (size_t)blk * MM * 3;
    if (tid == 0) { out[0] = lx; out[1] = ly; out[2] = lz; }

    for (int it = 1; it < MM; ++it) {
        int pp = it & 1;
        // distance update (no-FMA, fixed order to match numpy bitwise)
        float mv[8];
#pragma unroll
        for (int j = 0; j < 8; ++j) {
            float dx = px[j] - lx, dy = py[j] - ly, dz = pz[j] - lz;
            float d = __fadd_rn(__fadd_rn(__fmul_rn(dx, dx), __fmul_rn(dy, dy)),
                                __fmul_rn(dz, dz));
            float m = fminf(mind[j], d);
            mind[j] = m;
            mv[j] = m;
        }
        // tree argmax over the 8 candidates (assoc+comm -> order-free)
        unsigned chi[8], clo[8];
        float cx[8], cy[8], cz[8];
#pragma unroll
        for (int j = 0; j < 8; ++j) {
            chi[j] = __float_as_uint(mv[j]); clo[j] = lo_[j];
            cx[j] = px[j]; cy[j] = py[j]; cz[j] = pz[j];
        }
#pragma unroll
        for (int st = 1; st < 8; st <<= 1) {
#pragma unroll
            for (int j = 0; j < 8; j += 2 * st) {
                if (keyGT(chi[j + st], clo[j + st], chi[j], clo[j])) {
                    chi[j] = chi[j + st]; clo[j] = clo[j + st];
                    cx[j] = cx[j + st]; cy[j] = cy[j + st]; cz[j] = cz[j + st];
                }
            }
        }
        unsigned khi = chi[0], klo = clo[0];
        float wx = cx[0], wy = cy[0], wz = cz[0];

        // wave argmax via DPP (VALU pipe): full result lands in lane 63
#define DPP_STEP(CTRL) { \
            unsigned ohi = dppu<CTRL>(khi), olo = dppu<CTRL>(klo); \
            float ox = dppf<CTRL>(wx), oy = dppf<CTRL>(wy), oz = dppf<CTRL>(wz); \
            if (keyGT(ohi, olo, khi, klo)) { khi = ohi; klo = olo; wx = ox; wy = oy; wz = oz; } }
        DPP_STEP(0xB1)   // quad_perm xor1
        DPP_STEP(0x4E)   // quad_perm xor2
        DPP_STEP(0x141)  // row_half_mirror
        DPP_STEP(0x140)  // row_mirror
        DPP_STEP(0x142)  // row_bcast15
        DPP_STEP(0x143)  // row_bcast31
#undef DPP_STEP
        if ((tid & 63) == 63) {
            sA[pp][w] = make_float4(__uint_as_float(khi), __uint_as_float(klo), wx, wy);
            sB[pp][w] = wz;
        }
        __syncthreads();
        float4 a0 = sA[pp][0], a1 = sA[pp][1], a2 = sA[pp][2], a3 = sA[pp][3];
        float b0 = sB[pp][0], b1 = sB[pp][1], b2 = sB[pp][2], b3 = sB[pp][3];
        // merge 4 wave results (3 u64 merges)
        unsigned h0 = __float_as_uint(a0.x), l0 = __float_as_uint(a0.y);
        unsigned h1 = __float_as_uint(a1.x), l1 = __float_as_uint(a1.y);
        unsigned h2 = __float_as_uint(a2.x), l2 = __float_as_uint(a2.y);
        unsigned h3 = __float_as_uint(a3.x), l3 = __float_as_uint(a3.y);
        if (keyGT(h1, l1, h0, l0)) { h0 = h1; l0 = l1; a0.z = a1.z; a0.w = a1.w; b0 = b1; }
        if (keyGT(h3, l3, h2, l2)) { h2 = h3; l2 = l3; a2.z = a3.z; a2.w = a3.w; b2 = b3; }
        if (keyGT(h2, l2, h0, l0)) { h0 = h2; l0 = l2; a0.z = a2.z; a0.w = a2.w; b0 = b2; }
        lx = a0.z; ly = a0.w; lz = b0;   // block-uniform winner coords
        if (tid == 0) { out[it * 3 + 0] = lx; out[it * 3 + 1] = ly; out[it * 3 + 2] = lz; }
        // single barrier per iter: ping-pong buffer handles WAR across iterations
    }
}

// ---------------- Encode: one block per anchor (b,f,m); 256 threads = 2 dims each ----------------
__global__ __launch_bounds__(256) void encode_kernel(const float* __restrict__ input,
                                                     const float* __restrict__ W_d,
                                                     const float* __restrict__ W_f,
                                                     const float* __restrict__ W_pos,
                                                     const float* __restrict__ b_pos,
                                                     const float* __restrict__ anchor_xyz,
                                                     float* __restrict__ outp) {
    __shared__ float hx[2][KH], hy[2][KH], hz[2][KH];
    __shared__ int swtot[2][4];
    int bid = blockIdx.x;                 // b*512 + f*64 + m
    int b = bid >> 9;
    int rem = bid & 511;
    int f = rem >> 6;
    int m = rem & 63;
    int tid = threadIdx.x, lane = tid & 63, w = tid >> 6;

    const float* anc = anchor_xyz + (size_t)(((b << 3) + f) * MM + m) * 3;
    float ax = anc[0], ay = anc[1], az = anc[2];

    int d0 = tid, d1 = tid + 256;
    float4 wd0 = ((const float4*)W_d)[d0];
    float4 wd1 = ((const float4*)W_d)[d1];
    float  wf0 = W_f[d0], wf1 = W_f[d1];
    float p0 = -INFINITY, p1 = -INFINITY;

    for (int dt = -1; dt <= 1; ++dt) {
        int pp = (dt + 1) & 1;
        int frame = 2 * f + dt;
        frame = frame < 0 ? 0 : (frame > 14 ? 14 : frame);
        const float* src = input + ((size_t)(b * TT + frame)) * NN * 3;

        // thread t owns consecutive points [8t, 8t+8)
        float px[8], py[8], pz[8];
        const float4* s4 = (const float4*)(src + tid * 24);
        float4 v0 = s4[0], v1 = s4[1], v2 = s4[2], v3 = s4[3], v4 = s4[4], v5 = s4[5];
        px[0] = v0.x; py[0] = v0.y; pz[0] = v0.z;
        px[1] = v0.w; py[1] = v1.x; pz[1] = v1.y;
        px[2] = v1.z; py[2] = v1.w; pz[2] = v2.x;
        px[3] = v2.y; py[3] = v2.z; pz[3] = v2.w;
        px[4] = v3.x; py[4] = v3.y; pz[4] = v3.z;
        px[5] = v3.w; py[5] = v4.x; pz[5] = v4.y;
        px[6] = v4.z; py[6] = v4.w; pz[6] = v5.x;
        px[7] = v5.y; py[7] = v5.z; pz[7] = v5.w;

        unsigned hit = 0; int cnt = 0;
#pragma unroll
        for (int j = 0; j < 8; ++j) {
            float dx = ax - px[j], dy = ay - py[j], dz = az - pz[j];
            float d2 = __fadd_rn(__fadd_rn(__fmul_rn(dx, dx), __fmul_rn(dy, dy)),
                                 __fmul_rn(dz, dz));
            if (d2 < R2) { hit |= 1u << j; cnt++; }
        }
        // wave inclusive scan of cnt
        int s = cnt;
#pragma unroll
        for (int off = 1; off < 64; off <<= 1) {
            int o = __shfl_up(s, off);
            if (lane >= off) s += o;
        }
        if (lane == 63) swtot[pp][w] = s;
        __syncthreads();
        int wavebase = 0, total = 0;
#pragma unroll
        for (int ww = 0; ww < 4; ++ww) {
            int t2 = swtot[pp][ww];
            total += t2;
            if (ww < w) wavebase += t2;
        }
        int r = wavebase + s - cnt;   // exclusive global rank of this thread's first hit
#pragma unroll
        for (int j = 0; j < 8; ++j) {
            if (hit & (1u << j)) {
                if (r < KH) { hx[pp][r] = px[j]; hy[pp][r] = py[j]; hz[pp][r] = pz[j]; }
                r++;
            }
        }
        if (total == 0 && tid == 0) { hx[pp][0] = px[0]; hy[pp][0] = py[0]; hz[pp][0] = pz[0]; }
        __syncthreads();

        int nh = (total == 0) ? 1 : (total < KH ? total : KH);
        float dtf = (float)dt;
        // dual accumulators halve the dependent fmax chain (max is exactly assoc+comm)
        float q0 = -INFINITY, q1 = -INFINITY;
        int k = 0;
        for (; k + 2 <= nh; k += 2) {
            float gx0 = hx[pp][k],     gy0 = hy[pp][k],     gz0 = hz[pp][k];
            float gx1 = hx[pp][k + 1], gy1 = hy[pp][k + 1], gz1 = hz[pp][k + 1];
            float dx0 = gx0 - ax, dy0 = gy0 - ay, dz0 = gz0 - az;
            float dx1 = gx1 - ax, dy1 = gy1 - ay, dz1 = gz1 - az;
            float u0 = dx0 * wd0.x + dy0 * wd0.y + dz0 * wd0.z + dtf * wd0.w + gz0 * wf0;
            float u1 = dx0 * wd1.x + dy0 * wd1.y + dz0 * wd1.z + dtf * wd1.w + gz0 * wf1;
            float t0 = dx1 * wd0.x + dy1 * wd0.y + dz1 * wd0.z + dtf * wd0.w + gz1 * wf0;
            float t1 = dx1 * wd1.x + dy1 * wd1.y + dz1 * wd1.z + dtf * wd1.w + gz1 * wf1;
            p0 = fmaxf(p0, u0); p1 = fmaxf(p1, u1);
            q0 = fmaxf(q0, t0); q1 = fmaxf(q1, t1);
        }
        if (k < nh) {
            float gx0 = hx[pp][k], gy0 = hy[pp][k], gz0 = hz[pp][k];
            float dx0 = gx0 - ax, dy0 = gy0 - ay, dz0 = gz0 - az;
            float u0 = dx0 * wd0.x + dy0 * wd0.y + dz0 * wd0.z + dtf * wd0.w + gz0 * wf0;
            float u1 = dx0 * wd1.x + dy0 * wd1.y + dz0 * wd1.z + dtf * wd1.w + gz0 * wf1;
            p0 = fmaxf(p0, u0); p1 = fmaxf(p1, u1);
        }
        p0 = fmaxf(p0, q0); p1 = fmaxf(p1, q1);
        // no trailing barrier: ping-pong buffers handle WAR across dt
    }

    // epilogue: positional linear + bias + relu, float32 store
    float4 wp0 = ((const float4*)W_pos)[d0];
    float4 wp1 = ((const float4*)W_pos)[d1];
    float tv = (float)(f + 1);
    float pos0 = ax * wp0.x + ay * wp0.y + az * wp0.z + tv * wp0.w + b_pos[d0];
    float pos1 = ax * wp1.x + ay * wp1.y + az * wp1.z + tv * wp1.w + b_pos[d1];
    float o0 = fmaxf(pos0 + p0, 0.0f);
    float o1 = fmaxf(pos1 + p1, 0.0f);
    size_t row = ((size_t)b * (TO * MM) + f * MM + m) * DIMD;
    outp[row + d0] = o0;
    outp[row + d1] = o1;
}

extern "C" void kernel_launch(void* const* d_in, const int* in_sizes, int n_in,
                              void* d_out, int out_size, void* d_ws, size_t ws_size,
                              hipStream_t stream) {
    const float* input = (const float*)d_in[0];
    const float* W_d   = (const float*)d_in[1];
    const float* W_f   = (const float*)d_in[2];
    const float* W_pos = (const float*)d_in[3];
    const float* b_pos = (const float*)d_in[4];
    float* anchor = (float*)d_ws;   // 16*64*3 floats = 12 KB

    fps_kernel<<<16, 256, 0, stream>>>(input, anchor);
    encode_kernel<<<1024, 256, 0, stream>>>(input, W_d, W_f, W_pos, b_pos, anchor,
                                            (float*)d_out);
}